// Round 5
// baseline (83.560 us; speedup 1.0000x reference)
//
#include <hip/hip_runtime.h>
#include <hip/hip_bf16.h>

#define S_LEN 2048
#define DHEAD 128

typedef __bf16 bf16x8 __attribute__((ext_vector_type(8)));
typedef float  f32x16 __attribute__((ext_vector_type(16)));

union PK { __bf16 h[2]; unsigned u; };
union BW { unsigned w4[4]; bf16x8 v; };
union F4 { float4 v; float f[4]; };

struct TrueT  { static constexpr bool value = true;  };
struct FalseT { static constexpr bool value = false; };

__device__ __forceinline__ bf16x8 cvt8(float4 a, float4 b) {
  bf16x8 r;
  r[0] = (__bf16)a.x; r[1] = (__bf16)a.y; r[2] = (__bf16)a.z; r[3] = (__bf16)a.w;
  r[4] = (__bf16)b.x; r[5] = (__bf16)b.y; r[6] = (__bf16)b.z; r[7] = (__bf16)b.w;
  return r;
}

// Flash attention fwd, causal. Block = 4 waves, 32 q rows.
// Iteration = 128-key shared LDS tile (coalesced staged); wave w computes kv
// window [128i+32w, +32) -> 4-way kv-parity split, merged at end.
// S^T = mfma(K,Q) 32x32x16 -> in-register softmax; O^T = mfma(V^T, P^T).
// Raw barriers (no vmcnt drain); K(i+1) reg-prefetched across compute.
__global__ __launch_bounds__(256, 2) void attn_fwd(
    const float* __restrict__ Q, const float* __restrict__ K,
    const float* __restrict__ V, float* __restrict__ Out) {
  // [0,32768): K bf16 [128 kv][256B], col swz ^((kv&15)<<4)
  // [32768,65536): V^T bf16 [128 d][256B] pair-packed dwords, col swz ^((d&15)<<4)
  // epilogue overlay: Ob0@0 (32x132 f32), Ob1@16896, ml@36864, Lbuf@37888
  __shared__ __align__(16) char lds[65536];
  char* Kl = lds;
  char* Vl = lds + 32768;

  const int tid  = threadIdx.x;
  const int w    = tid >> 6;
  const int lane = tid & 63;
  const int h    = lane >> 5;
  const int lq   = lane & 31;

  const int bi    = blockIdx.x;
  const int batch = bi & 7;                                      // XCD L2 locality
  const int T     = (bi < 256) ? (63 - (bi >> 3)) : ((bi - 256) >> 3);  // long+short pair
  const int q0    = T << 5;
  const int q     = q0 + lq;

  const float* Qb = Q + (size_t)batch * S_LEN * DHEAD;
  const float* Kb = K + (size_t)batch * S_LEN * DHEAD;
  const float* Vb = V + (size_t)batch * S_LEN * DHEAD;

  // ---- staging maps ----
  const int srow = tid >> 5;        // K: rows srow+8j, 0..127
  const int scol = tid & 31;        // K: floats scol*4..+3 (full 128 coverage)
  const int va   = tid & 63;        // V: kv pair index (rows 2va, 2va+1)
  const int vd0  = (tid >> 6) << 5; // V: d window [vd0, vd0+32)

  float4 kreg[16];                  // K tile prefetch
  F4 vr0[8], vr1[8];                // V rows 2va / 2va+1, floats vd0+4c..+3

  auto issueK = [&](int kb) {
#pragma unroll
    for (int j = 0; j < 16; ++j)
      kreg[j] = *(const float4*)(Kb + (size_t)(kb + srow + 8 * j) * DHEAD + scol * 4);
  };
  auto issueV = [&](int kb) {
    const float* vp = Vb + (size_t)(kb + 2 * va) * DHEAD + vd0;
#pragma unroll
    for (int c = 0; c < 8; ++c) {
      vr0[c].v = *(const float4*)(vp + 4 * c);
      vr1[c].v = *(const float4*)(vp + DHEAD + 4 * c);
    }
  };
  auto writeK = [&]() {
#pragma unroll
    for (int j = 0; j < 16; ++j) {
      const int row = srow + 8 * j;
      PK p0, p1;
      p0.h[0] = (__bf16)kreg[j].x; p0.h[1] = (__bf16)kreg[j].y;
      p1.h[0] = (__bf16)kreg[j].z; p1.h[1] = (__bf16)kreg[j].w;
      *(uint2*)(Kl + row * 256 + ((scol * 8) ^ ((row & 15) << 4))) = make_uint2(p0.u, p1.u);
    }
  };
  auto writeV = [&]() {
#pragma unroll
    for (int c = 0; c < 8; ++c) {
#pragma unroll
      for (int dd = 0; dd < 4; ++dd) {
        const int d = vd0 + 4 * c + dd;
        PK pk;
        pk.h[0] = (__bf16)vr0[c].f[dd];   // kv = 2va
        pk.h[1] = (__bf16)vr1[c].f[dd];   // kv = 2va+1
        *(unsigned*)(Vl + d * 256 + ((4 * va) ^ ((d & 15) << 4))) = pk.u;
      }
    }
  };

  // ---- Q fragments (B-operand: col=q, k=8h+j), pre-scaled ----
  const float scale = 0.08838834764831845f;
  bf16x8 qf[8];
  {
    const float* qp = Qb + (size_t)q * DHEAD + 8 * h;
#pragma unroll
    for (int ks = 0; ks < 8; ++ks) {
      float4 a = *(const float4*)(qp + 16 * ks);
      float4 b = *(const float4*)(qp + 16 * ks + 4);
      a.x *= scale; a.y *= scale; a.z *= scale; a.w *= scale;
      b.x *= scale; b.y *= scale; b.z *= scale; b.w *= scale;
      qf[ks] = cvt8(a, b);
    }
  }

  float  mrun = -INFINITY, lrun = 0.f;
  f32x16 ob[4];
#pragma unroll
  for (int db = 0; db < 4; ++db)
#pragma unroll
    for (int r = 0; r < 16; ++r) ob[db][r] = 0.f;

  const int kvo = 32 * w;            // wave's kv offset within a 128-key tile
  const int sw  = (lq & 15) << 4;    // read swizzle ((row or d)&15 == lq&15)

  auto tile = [&](int kb, auto diagc) {
    constexpr bool DIAG = decltype(diagc)::value;
    const int rb = (kvo + lq) * 256;

    // ---- S^T = K * Q^T ----
    f32x16 sa, sb;
#pragma unroll
    for (int r = 0; r < 16; ++r) { sa[r] = 0.f; sb[r] = 0.f; }
    __builtin_amdgcn_s_setprio(1);
#pragma unroll
    for (int ks = 0; ks < 4; ++ks) {
      bf16x8 kf = *(const bf16x8*)(Kl + rb + ((32 * ks + 16 * h) ^ sw));
      sa = __builtin_amdgcn_mfma_f32_32x32x16_bf16(kf, qf[ks], sa, 0, 0, 0);
    }
#pragma unroll
    for (int ks = 4; ks < 8; ++ks) {
      bf16x8 kf = *(const bf16x8*)(Kl + rb + ((32 * ks + 16 * h) ^ sw));
      sb = __builtin_amdgcn_mfma_f32_32x32x16_bf16(kf, qf[ks], sb, 0, 0, 0);
    }
    __builtin_amdgcn_s_setprio(0);
    f32x16 sv;
#pragma unroll
    for (int r = 0; r < 16; ++r) sv[r] = sa[r] + sb[r];

    // ---- in-register softmax (lane owns P column of row q) ----
    bool ok[16];
    if constexpr (DIAG) {
#pragma unroll
      for (int r = 0; r < 16; ++r) {
        const int kvr = kb + (r & 3) + 8 * (r >> 2) + 4 * h;
        ok[r] = (kvr <= q);
        sv[r] = ok[r] ? sv[r] : -INFINITY;
      }
    }
    float mx = sv[0];
#pragma unroll
    for (int r = 1; r < 16; ++r) mx = fmaxf(mx, sv[r]);
    mx = fmaxf(mx, __shfl_xor(mx, 32));

    float mnew = mrun;                       // T13 defer-max
    if (__any(mx > mrun + 8.f)) {
      mnew = fmaxf(mrun, mx);
      const float alpha = __expf(mrun - mnew);
      lrun *= alpha;
#pragma unroll
      for (int db = 0; db < 4; ++db)
#pragma unroll
        for (int r = 0; r < 16; ++r) ob[db][r] *= alpha;
      mrun = mnew;
    }

    float pv[16];
    float rsum = 0.f;
#pragma unroll
    for (int r = 0; r < 16; ++r) {
      float e = __expf(sv[r] - mnew);
      if constexpr (DIAG) e = ok[r] ? e : 0.f;
      pv[r] = e;
      rsum += e;
    }
    rsum += __shfl_xor(rsum, 32);
    lrun += rsum;

    // ---- P -> bf16 packs + half-wave exchange (T12) ----
    unsigned c[8];
#pragma unroll
    for (int i = 0; i < 8; ++i) {
      PK pk;
      pk.h[0] = (__bf16)pv[2 * i];
      pk.h[1] = (__bf16)pv[2 * i + 1];
      c[i] = pk.u;
    }
    const unsigned e0 = (unsigned)__shfl_xor((int)(h ? c[0] : c[2]), 32);
    const unsigned e1 = (unsigned)__shfl_xor((int)(h ? c[1] : c[3]), 32);
    const unsigned e2 = (unsigned)__shfl_xor((int)(h ? c[4] : c[6]), 32);
    const unsigned e3 = (unsigned)__shfl_xor((int)(h ? c[5] : c[7]), 32);
    BW pb0, pb1;
    pb0.w4[0] = h ? e0   : c[0];
    pb0.w4[1] = h ? e1   : c[1];
    pb0.w4[2] = h ? c[2] : e0;
    pb0.w4[3] = h ? c[3] : e1;
    pb1.w4[0] = h ? e2   : c[4];
    pb1.w4[1] = h ? e3   : c[5];
    pb1.w4[2] = h ? c[6] : e2;
    pb1.w4[3] = h ? c[7] : e3;

    // ---- PV: O^T += V^T * P^T ----
    __builtin_amdgcn_s_setprio(1);
#pragma unroll
    for (int db = 0; db < 4; ++db) {
      const char* vp = Vl + (32 * db + lq) * 256;
      bf16x8 a0 = *(const bf16x8*)(vp + ((2 * kvo + 16 * h) ^ sw));
      ob[db] = __builtin_amdgcn_mfma_f32_32x32x16_bf16(a0, pb0.v, ob[db], 0, 0, 0);
      bf16x8 a1 = *(const bf16x8*)(vp + ((2 * kvo + 32 + 16 * h) ^ sw));
      ob[db] = __builtin_amdgcn_mfma_f32_32x32x16_bf16(a1, pb1.v, ob[db], 0, 0, 0);
    }
    __builtin_amdgcn_s_setprio(0);
  };

  // ---- main pipelined loop ----
  const int nit = (q0 + 159) >> 7;   // ceil((q0+32)/128)
  issueK(0);
  for (int i = 0; i < nit; ++i) {
    issueV(i << 7);                              // in flight across barrier + K-write
    __builtin_amdgcn_s_barrier();                // LDS free (no vmcnt drain)
    __builtin_amdgcn_sched_barrier(0);
    writeK();                                    // kreg prefetched last iteration
    writeV();
    __builtin_amdgcn_sched_barrier(0);
    if (i + 1 < nit) issueK((i + 1) << 7);       // hidden under compute
    asm volatile("s_waitcnt lgkmcnt(0)" ::: "memory");
    __builtin_amdgcn_s_barrier();                // tile ready (no vmcnt drain)
    __builtin_amdgcn_sched_barrier(0);
    const int kb = (i << 7) + kvo;
    if (kb <= q0) {
      if (kb == q0) tile(kb, TrueT{});
      else          tile(kb, FalseT{});
    }
  }

  // ================= merge 4 kv-parity partials =================
  __syncthreads();
  float2* ml   = (float2*)(lds + 36864);
  float*  Lbuf = (float*)(lds + 37888);
  float*  Ob0  = (float*)(lds);
  float*  Ob1  = (float*)(lds + 16896);

  if (h == 0) ml[w * 32 + lq] = make_float2(mrun, lrun);
  __syncthreads();

  float M = -INFINITY;
#pragma unroll
  for (int ww = 0; ww < 4; ++ww) M = fmaxf(M, ml[ww * 32 + lq].x);
  float L = 0.f;
#pragma unroll
  for (int ww = 0; ww < 4; ++ww) {
    float2 v = ml[ww * 32 + lq];
    L += v.y * __expf(v.x - M);
  }
  const float fw = __expf(mrun - M);   // 0 for idle waves (mrun = -inf)
  if (w == 0 && h == 0) Lbuf[lq] = 1.f / L;

  float* Ob = (w & 1) ? Ob1 : Ob0;
  if (w < 2) {
#pragma unroll
    for (int db = 0; db < 4; ++db)
#pragma unroll
      for (int rr = 0; rr < 4; ++rr) {
        float4 val = { ob[db][4 * rr + 0] * fw, ob[db][4 * rr + 1] * fw,
                       ob[db][4 * rr + 2] * fw, ob[db][4 * rr + 3] * fw };
        *(float4*)(Ob + lq * 132 + 32 * db + 8 * rr + 4 * h) = val;
      }
  }
  __syncthreads();
  if (w >= 2) {
#pragma unroll
    for (int db = 0; db < 4; ++db)
#pragma unroll
      for (int rr = 0; rr < 4; ++rr) {
        float* p = Ob + lq * 132 + 32 * db + 8 * rr + 4 * h;
        float4 cur = *(float4*)p;
        cur.x += ob[db][4 * rr + 0] * fw;
        cur.y += ob[db][4 * rr + 1] * fw;
        cur.z += ob[db][4 * rr + 2] * fw;
        cur.w += ob[db][4 * rr + 3] * fw;
        *(float4*)p = cur;
      }
  }
  __syncthreads();

  // ---- cooperative coalesced store ----
  const int row = tid >> 3;
  const int d0  = (tid & 7) * 16;
  const float inv = Lbuf[row];
  float* orow = Out + ((size_t)(batch * S_LEN + q0 + row)) * DHEAD + d0;
#pragma unroll
  for (int j = 0; j < 4; ++j) {
    float4 a = *(float4*)(Ob0 + row * 132 + d0 + 4 * j);
    float4 b = *(float4*)(Ob1 + row * 132 + d0 + 4 * j);
    float4 o = { (a.x + b.x) * inv, (a.y + b.y) * inv,
                 (a.z + b.z) * inv, (a.w + b.w) * inv };
    *(float4*)(orow + 4 * j) = o;
  }
}

extern "C" void kernel_launch(void* const* d_in, const int* in_sizes, int n_in,
                              void* d_out, int out_size, void* d_ws, size_t ws_size,
                              hipStream_t stream) {
  const float* q = (const float*)d_in[0];
  const float* k = (const float*)d_in[1];
  const float* v = (const float*)d_in[2];
  float* out = (float*)d_out;
  const int B = in_sizes[0] / (S_LEN * DHEAD);
  dim3 grid(B * (S_LEN / 32));
  attn_fwd<<<grid, dim3(256), 0, stream>>>(q, k, v, out);
}